// Round 1
// baseline (236.531 us; speedup 1.0000x reference)
//
#include <hip/hip_runtime.h>

#define B_ 8
#define S_ 4096
#define D_ 1024
#define N_ 128
#define K_ 8
#define NEG_INF_ (-1e9f)

// ---------------- Kernel 1: per-sentence segment sums + counts ----------------
// One block per (b, n). sentence_indicator is sorted along S, so sentence n is
// the contiguous range [lower_bound(n), lower_bound(n+1)). 256 threads, each
// owns a float4 of D=1024. No atomics needed.
__global__ void seg_pool_kernel(const float* __restrict__ h,
                                const int* __restrict__ ind,
                                float* __restrict__ seg_sum,   // [B,N,D]
                                float* __restrict__ counts) {  // [B,N]
    const int bn = blockIdx.x;
    const int b = bn / N_;
    const int n = bn % N_;
    const int tid = threadIdx.x;
    const int* indb = ind + b * S_;

    // lower_bound(x): first index i with indb[i] >= x  (redundant per-thread,
    // same addresses -> broadcast loads)
    int s0, s1;
    {
        int lo = 0, hi = S_;
        while (lo < hi) { int mid = (lo + hi) >> 1; if (indb[mid] < n) lo = mid + 1; else hi = mid; }
        s0 = lo;
        lo = s0; hi = S_;
        while (lo < hi) { int mid = (lo + hi) >> 1; if (indb[mid] < n + 1) lo = mid + 1; else hi = mid; }
        s1 = lo;
    }

    float4 acc = make_float4(0.f, 0.f, 0.f, 0.f);
    const float* hb = h + (size_t)b * S_ * D_;
    const int dofs = tid * 4;
    for (int s = s0; s < s1; ++s) {
        const float4 v = *reinterpret_cast<const float4*>(hb + (size_t)s * D_ + dofs);
        acc.x += v.x; acc.y += v.y; acc.z += v.z; acc.w += v.w;
    }
    *reinterpret_cast<float4*>(seg_sum + (size_t)bn * D_ + dofs) = acc;
    if (tid == 0) counts[bn] = (float)(s1 - s0);
}

// ---------------- Kernel 2: greedy selection loop ----------------
// One block per batch. dot_seg[n] = seg_sum[b,n,:].w computed once; K-loop is
// then purely scalar per sentence.
__global__ void select_kernel(const float* __restrict__ seg_sum,  // [B,N,D]
                              const float* __restrict__ counts,   // [B,N]
                              const float* __restrict__ cls_w,    // [D]
                              const float* __restrict__ cls_b,    // [1]
                              float* __restrict__ out_selected,   // [B,N]
                              float* __restrict__ out_logits,     // [K,B,N]
                              float* __restrict__ sel_ws) {       // [B,N]
    const int b = blockIdx.x;
    const int tid = threadIdx.x;

    __shared__ float w[D_];
    __shared__ float dot_seg[N_];
    __shared__ float lens[N_];
    __shared__ float smask[N_];
    __shared__ float sel[N_];
    __shared__ float red_val[256];
    __shared__ int   red_idx[256];
    __shared__ float s_dotcur, s_lencur;
    __shared__ int   s_pick;

    for (int d = tid; d < D_; d += 256) w[d] = cls_w[d];
    if (tid < N_) {
        float c = counts[b * N_ + tid];
        lens[tid]  = fmaxf(c, 1.0f);
        smask[tid] = (c > 0.f) ? 1.f : 0.f;
        sel[tid]   = 0.f;
    }
    if (tid == 0) { s_dotcur = 0.f; s_lencur = 0.f; }
    __syncthreads();

    // dot_seg: wave wv handles sentence n = wv, wv+4, ...
    const int wv = tid >> 6, lane = tid & 63;
    for (int n = wv; n < N_; n += 4) {
        const float* p = seg_sum + ((size_t)b * N_ + n) * D_;
        float acc = 0.f;
        for (int j = lane; j < D_; j += 64) acc += p[j] * w[j];
        for (int off = 32; off > 0; off >>= 1) acc += __shfl_down(acc, off, 64);
        if (lane == 0) dot_seg[n] = acc;
    }
    __syncthreads();

    const float bias = cls_b[0];
    for (int k = 0; k < K_; ++k) {
        float logit = -3.0e38f;
        if (tid < N_) {
            logit = (s_dotcur + dot_seg[tid]) / (s_lencur + lens[tid]) + bias;
            logit = (smask[tid] > 0.f) ? logit : NEG_INF_;
            out_logits[(size_t)k * (B_ * N_) + b * N_ + tid] = logit;
        }
        red_val[tid] = logit;
        red_idx[tid] = tid;
        __syncthreads();
        // argmax with first-index tiebreak (matches jnp.argmax)
        for (int off = 128; off > 0; off >>= 1) {
            if (tid < off) {
                float v2 = red_val[tid + off]; int i2 = red_idx[tid + off];
                if (v2 > red_val[tid] || (v2 == red_val[tid] && i2 < red_idx[tid])) {
                    red_val[tid] = v2; red_idx[tid] = i2;
                }
            }
            __syncthreads();
        }
        if (tid == 0) {
            const int idx = red_idx[0];
            s_pick = idx;
            s_dotcur += dot_seg[idx];
            s_lencur += lens[idx];
            smask[idx] = 0.f;
            sel[idx] = 1.f;   // clip(sum of one-hots, 0, 1)
        }
        __syncthreads();
    }

    if (tid < N_) {
        out_selected[b * N_ + tid] = sel[tid];
        sel_ws[b * N_ + tid] = sel[tid];
    }
}

// ---------------- Kernel 3: apply mask to tokens ----------------
// One block per token (b,s): 256 threads x float4 covers D=1024.
__global__ void mask_kernel(const float* __restrict__ h,
                            const int* __restrict__ ind,
                            const float* __restrict__ sel_ws,   // [B,N]
                            float* __restrict__ out_mask,       // [B,S]
                            float* __restrict__ out_masked) {   // [B,S,D]
    const int token = blockIdx.x;          // b*S + s
    const int b = token >> 12;             // S = 4096
    const int tid = threadIdx.x;
    const int id = ind[token];
    const float m = sel_ws[b * N_ + id];
    if (tid == 0) out_mask[token] = m;
    const size_t base = (size_t)token * D_ + tid * 4;
    const float4 v = *reinterpret_cast<const float4*>(h + base);
    float4 r = make_float4(v.x * m, v.y * m, v.z * m, v.w * m);
    *reinterpret_cast<float4*>(out_masked + base) = r;
}

extern "C" void kernel_launch(void* const* d_in, const int* in_sizes, int n_in,
                              void* d_out, int out_size, void* d_ws, size_t ws_size,
                              hipStream_t stream) {
    const float* h     = (const float*)d_in[0];
    const int*   ind   = (const int*)d_in[1];
    const float* cls_w = (const float*)d_in[2];
    const float* cls_b = (const float*)d_in[3];

    float* out = (float*)d_out;
    float* out_selected = out;                         // [B,N]    1024
    float* out_logits   = out + 1024;                  // [K,B,N]  8192
    float* out_mask     = out + 1024 + 8192;           // [B,S]    32768
    float* out_masked   = out + 1024 + 8192 + 32768;   // [B,S,D]

    char* ws = (char*)d_ws;
    float* seg_sum = (float*)ws;                                   // B*N*D = 4 MB
    float* cnts    = (float*)(ws + (size_t)B_ * N_ * D_ * 4);      // B*N
    float* sel_ws  = (float*)(ws + (size_t)B_ * N_ * D_ * 4 + B_ * N_ * 4);

    seg_pool_kernel<<<dim3(B_ * N_), dim3(256), 0, stream>>>(h, ind, seg_sum, cnts);
    select_kernel<<<dim3(B_), dim3(256), 0, stream>>>(seg_sum, cnts, cls_w, cls_b,
                                                      out_selected, out_logits, sel_ws);
    mask_kernel<<<dim3(B_ * S_), dim3(256), 0, stream>>>(h, ind, sel_ws, out_mask, out_masked);
}

// Round 2
// 59.767 us; speedup vs baseline: 3.9576x; 3.9576x over previous
//
#include <hip/hip_runtime.h>

#define B_ 8
#define S_ 4096
#define D_ 1024
#define N_ 128
#define K_ 8
#define NEG_INF_ (-1e9f)

// ---------------- Kernel 1: per-sentence pooled dot + counts ----------------
// One block per (b, n). sentence_indicator is sorted along S, so sentence n is
// the contiguous range [lower_bound(n), lower_bound(n+1)). Each thread owns a
// float4 slice of D=1024, accumulates the segment sum in registers, dots it
// with cls_w, block-reduces. seg_sum is never materialized.
__global__ void seg_dot_kernel(const float* __restrict__ h,
                               const int* __restrict__ ind,
                               const float* __restrict__ cls_w,
                               float* __restrict__ dot_seg,   // [B,N]
                               float* __restrict__ counts) {  // [B,N]
    const int bn = blockIdx.x;
    const int b = bn / N_;
    const int n = bn % N_;
    const int tid = threadIdx.x;
    const int* indb = ind + b * S_;

    int s0, s1;
    {
        int lo = 0, hi = S_;
        while (lo < hi) { int mid = (lo + hi) >> 1; if (indb[mid] < n) lo = mid + 1; else hi = mid; }
        s0 = lo;
        lo = s0; hi = S_;
        while (lo < hi) { int mid = (lo + hi) >> 1; if (indb[mid] < n + 1) lo = mid + 1; else hi = mid; }
        s1 = lo;
    }

    const int dofs = tid * 4;
    float4 acc = make_float4(0.f, 0.f, 0.f, 0.f);
    const float* hb = h + (size_t)b * S_ * D_;
    for (int s = s0; s < s1; ++s) {
        const float4 v = *reinterpret_cast<const float4*>(hb + (size_t)s * D_ + dofs);
        acc.x += v.x; acc.y += v.y; acc.z += v.z; acc.w += v.w;
    }
    const float4 w4 = *reinterpret_cast<const float4*>(cls_w + dofs);
    float partial = acc.x * w4.x + acc.y * w4.y + acc.z * w4.z + acc.w * w4.w;

    // wave reduce (64) then cross-wave via LDS
    for (int off = 32; off > 0; off >>= 1) partial += __shfl_down(partial, off, 64);
    __shared__ float wsum[4];
    const int wv = tid >> 6, lane = tid & 63;
    if (lane == 0) wsum[wv] = partial;
    __syncthreads();
    if (tid == 0) {
        dot_seg[bn] = wsum[0] + wsum[1] + wsum[2] + wsum[3];
        counts[bn] = (float)(s1 - s0);
    }
}

// ---------------- Kernel 2: greedy selection loop (tiny) ----------------
// One block per batch, 128 threads (one per sentence). Pure scalar K-loop.
__global__ void select_kernel(const float* __restrict__ dot_seg,  // [B,N]
                              const float* __restrict__ counts,   // [B,N]
                              const float* __restrict__ cls_b,    // [1]
                              float* __restrict__ out_selected,   // [B,N]
                              float* __restrict__ out_logits,     // [K,B,N]
                              float* __restrict__ sel_ws) {       // [B,N]
    const int b = blockIdx.x;
    const int tid = threadIdx.x;  // 0..127 == sentence id

    __shared__ float red_val[N_];
    __shared__ int   red_idx[N_];
    __shared__ float s_dotcur, s_lencur;

    const float dseg = dot_seg[b * N_ + tid];
    const float c    = counts[b * N_ + tid];
    const float len  = fmaxf(c, 1.0f);
    float smask = (c > 0.f) ? 1.f : 0.f;
    float sel   = 0.f;
    if (tid == 0) { s_dotcur = 0.f; s_lencur = 0.f; }
    const float bias = cls_b[0];
    __syncthreads();

    for (int k = 0; k < K_; ++k) {
        float logit = (s_dotcur + dseg) / (s_lencur + len) + bias;
        logit = (smask > 0.f) ? logit : NEG_INF_;
        out_logits[(size_t)k * (B_ * N_) + b * N_ + tid] = logit;
        red_val[tid] = logit;
        red_idx[tid] = tid;
        __syncthreads();
        for (int off = 64; off > 0; off >>= 1) {
            if (tid < off) {
                float v2 = red_val[tid + off]; int i2 = red_idx[tid + off];
                if (v2 > red_val[tid] || (v2 == red_val[tid] && i2 < red_idx[tid])) {
                    red_val[tid] = v2; red_idx[tid] = i2;
                }
            }
            __syncthreads();
        }
        const int pick = red_idx[0];
        if (tid == pick) { smask = 0.f; sel = 1.f; }
        if (tid == 0) {
            s_dotcur += red_val[0] != NEG_INF_ ? 0.f : 0.f;  // placeholder, real update below
        }
        __syncthreads();
        if (tid == pick) {
            s_dotcur += dseg;
            s_lencur += len;
        }
        __syncthreads();
    }

    out_selected[b * N_ + tid] = sel;
    sel_ws[b * N_ + tid] = sel;
}

// ---------------- Kernel 3: apply mask to tokens ----------------
// One block per token. Non-selected tokens write zeros without reading h.
__global__ void mask_kernel(const float* __restrict__ h,
                            const int* __restrict__ ind,
                            const float* __restrict__ sel_ws,   // [B,N]
                            float* __restrict__ out_mask,       // [B,S]
                            float* __restrict__ out_masked) {   // [B,S,D]
    const int token = blockIdx.x;          // b*S + s
    const int b = token >> 12;             // S = 4096
    const int tid = threadIdx.x;
    const int id = ind[token];
    const float m = sel_ws[b * N_ + id];
    if (tid == 0) out_mask[token] = m;
    const size_t base = (size_t)token * D_ + tid * 4;
    if (m == 0.f) {
        *reinterpret_cast<float4*>(out_masked + base) = make_float4(0.f, 0.f, 0.f, 0.f);
    } else {
        const float4 v = *reinterpret_cast<const float4*>(h + base);
        *reinterpret_cast<float4*>(out_masked + base) =
            make_float4(v.x * m, v.y * m, v.z * m, v.w * m);
    }
}

extern "C" void kernel_launch(void* const* d_in, const int* in_sizes, int n_in,
                              void* d_out, int out_size, void* d_ws, size_t ws_size,
                              hipStream_t stream) {
    const float* h     = (const float*)d_in[0];
    const int*   ind   = (const int*)d_in[1];
    const float* cls_w = (const float*)d_in[2];
    const float* cls_b = (const float*)d_in[3];

    float* out = (float*)d_out;
    float* out_selected = out;                         // [B,N]    1024
    float* out_logits   = out + 1024;                  // [K,B,N]  8192
    float* out_mask     = out + 1024 + 8192;           // [B,S]    32768
    float* out_masked   = out + 1024 + 8192 + 32768;   // [B,S,D]

    char* ws = (char*)d_ws;
    float* dot_seg = (float*)ws;                              // B*N
    float* cnts    = (float*)(ws + B_ * N_ * 4);              // B*N
    float* sel_ws  = (float*)(ws + 2 * B_ * N_ * 4);          // B*N

    seg_dot_kernel<<<dim3(B_ * N_), dim3(256), 0, stream>>>(h, ind, cls_w, dot_seg, cnts);
    select_kernel<<<dim3(B_), dim3(N_), 0, stream>>>(dot_seg, cnts, cls_b,
                                                     out_selected, out_logits, sel_ws);
    mask_kernel<<<dim3(B_ * S_), dim3(256), 0, stream>>>(h, ind, sel_ws, out_mask, out_masked);
}

// Round 3
// 58.439 us; speedup vs baseline: 4.0475x; 1.0227x over previous
//
#include <hip/hip_runtime.h>

#define B_ 8
#define S_ 4096
#define D_ 1024
#define N_ 128
#define K_ 8
#define NEG_INF_ (-1e9f)

// ---------------- Kernel 1: per-token dot with cls_w (balanced GEMV) ----------
// One wave per token per iteration. Lane l reads float4 at d = j*256 + l*4,
// j=0..3 -> each load instruction covers a contiguous 1KB. Work is identical
// for every wave: no data-dependent imbalance.
__global__ void tok_dot_kernel(const float* __restrict__ h,
                               const float* __restrict__ cls_w,
                               float* __restrict__ tok_dot) {   // [B*S]
    const int lane = threadIdx.x & 63;
    const int gw = (blockIdx.x << 2) + (threadIdx.x >> 6);  // global wave id, 0..8191
    const int dofs = lane * 4;

    const float4 w0 = *reinterpret_cast<const float4*>(cls_w + 0 * 256 + dofs);
    const float4 w1 = *reinterpret_cast<const float4*>(cls_w + 1 * 256 + dofs);
    const float4 w2 = *reinterpret_cast<const float4*>(cls_w + 2 * 256 + dofs);
    const float4 w3 = *reinterpret_cast<const float4*>(cls_w + 3 * 256 + dofs);

    for (int token = gw; token < B_ * S_; token += 8192) {
        const float* p = h + (size_t)token * D_;
        const float4 v0 = *reinterpret_cast<const float4*>(p + 0 * 256 + dofs);
        const float4 v1 = *reinterpret_cast<const float4*>(p + 1 * 256 + dofs);
        const float4 v2 = *reinterpret_cast<const float4*>(p + 2 * 256 + dofs);
        const float4 v3 = *reinterpret_cast<const float4*>(p + 3 * 256 + dofs);
        float acc = v0.x * w0.x + v0.y * w0.y + v0.z * w0.z + v0.w * w0.w
                  + v1.x * w1.x + v1.y * w1.y + v1.z * w1.z + v1.w * w1.w
                  + v2.x * w2.x + v2.y * w2.y + v2.z * w2.z + v2.w * w2.w
                  + v3.x * w3.x + v3.y * w3.y + v3.z * w3.z + v3.w * w3.w;
        for (int off = 32; off > 0; off >>= 1) acc += __shfl_down(acc, off, 64);
        if (lane == 0) tok_dot[token] = acc;
    }
}

// ---------------- Kernel 2: segment-sum of scalars + greedy selection --------
// One block per batch. Stage tok_dot row (16 KB) + ind row (16 KB) in LDS;
// thread n (<128) serially sums its sentence's token dots in sorted order
// (deterministic, same association order as the reference segment_sum), then
// the K-step argmax loop runs on 128 scalars.
__global__ void select_kernel(const float* __restrict__ tok_dot,  // [B,S]
                              const int* __restrict__ ind,        // [B,S]
                              const float* __restrict__ cls_b,    // [1]
                              float* __restrict__ out_selected,   // [B,N]
                              float* __restrict__ out_logits,     // [K,B,N]
                              float* __restrict__ sel_ws) {       // [B,N]
    const int b = blockIdx.x;
    const int tid = threadIdx.x;  // 256 threads

    __shared__ float td[S_];
    __shared__ int   si[S_];
    __shared__ float red_val[N_];
    __shared__ int   red_idx[N_];
    __shared__ float s_dotcur, s_lencur;

    for (int s = tid; s < S_; s += 256) {
        td[s] = tok_dot[b * S_ + s];
        si[s] = ind[b * S_ + s];
    }
    if (tid == 0) { s_dotcur = 0.f; s_lencur = 0.f; }
    __syncthreads();

    float dseg = 0.f, len = 1.f, smask = 0.f, sel = 0.f;
    if (tid < N_) {
        const int n = tid;
        int lo = 0, hi = S_;
        while (lo < hi) { int mid = (lo + hi) >> 1; if (si[mid] < n) lo = mid + 1; else hi = mid; }
        const int s0 = lo;
        lo = s0; hi = S_;
        while (lo < hi) { int mid = (lo + hi) >> 1; if (si[mid] < n + 1) lo = mid + 1; else hi = mid; }
        const int s1 = lo;
        float acc = 0.f;
        for (int s = s0; s < s1; ++s) acc += td[s];
        dseg  = acc;
        len   = fmaxf((float)(s1 - s0), 1.0f);
        smask = (s1 > s0) ? 1.f : 0.f;
    }
    const float bias = cls_b[0];
    __syncthreads();

    for (int k = 0; k < K_; ++k) {
        if (tid < N_) {
            float logit = (s_dotcur + dseg) / (s_lencur + len) + bias;
            logit = (smask > 0.f) ? logit : NEG_INF_;
            out_logits[(size_t)k * (B_ * N_) + b * N_ + tid] = logit;
            red_val[tid] = logit;
            red_idx[tid] = tid;
        }
        __syncthreads();
        for (int off = 64; off > 0; off >>= 1) {
            if (tid < off) {
                float v2 = red_val[tid + off]; int i2 = red_idx[tid + off];
                if (v2 > red_val[tid] || (v2 == red_val[tid] && i2 < red_idx[tid])) {
                    red_val[tid] = v2; red_idx[tid] = i2;
                }
            }
            __syncthreads();
        }
        const int pick = red_idx[0];
        if (tid == pick) {
            smask = 0.f; sel = 1.f;
            s_dotcur += dseg;
            s_lencur += len;
        }
        __syncthreads();
    }

    if (tid < N_) {
        out_selected[b * N_ + tid] = sel;
        sel_ws[b * N_ + tid] = sel;
    }
}

// ---------------- Kernel 3: apply mask to tokens ----------------
// 4 tokens per block. Non-selected tokens write zeros without reading h.
__global__ void mask_kernel(const float* __restrict__ h,
                            const int* __restrict__ ind,
                            const float* __restrict__ sel_ws,   // [B,N]
                            float* __restrict__ out_mask,       // [B,S]
                            float* __restrict__ out_masked) {   // [B,S,D]
    const int t0 = blockIdx.x << 2;
    const int tid = threadIdx.x;
    #pragma unroll
    for (int i = 0; i < 4; ++i) {
        const int token = t0 + i;              // b*S + s
        const int b = token >> 12;             // S = 4096
        const float m = sel_ws[b * N_ + ind[token]];
        if (tid == 0) out_mask[token] = m;
        const size_t base = (size_t)token * D_ + tid * 4;
        if (m == 0.f) {
            *reinterpret_cast<float4*>(out_masked + base) = make_float4(0.f, 0.f, 0.f, 0.f);
        } else {
            const float4 v = *reinterpret_cast<const float4*>(h + base);
            *reinterpret_cast<float4*>(out_masked + base) =
                make_float4(v.x * m, v.y * m, v.z * m, v.w * m);
        }
    }
}

extern "C" void kernel_launch(void* const* d_in, const int* in_sizes, int n_in,
                              void* d_out, int out_size, void* d_ws, size_t ws_size,
                              hipStream_t stream) {
    const float* h     = (const float*)d_in[0];
    const int*   ind   = (const int*)d_in[1];
    const float* cls_w = (const float*)d_in[2];
    const float* cls_b = (const float*)d_in[3];

    float* out = (float*)d_out;
    float* out_selected = out;                         // [B,N]    1024
    float* out_logits   = out + 1024;                  // [K,B,N]  8192
    float* out_mask     = out + 1024 + 8192;           // [B,S]    32768
    float* out_masked   = out + 1024 + 8192 + 32768;   // [B,S,D]

    char* ws = (char*)d_ws;
    float* tok_dot = (float*)ws;                              // B*S floats = 128 KB
    float* sel_ws  = (float*)(ws + (size_t)B_ * S_ * 4);      // B*N

    tok_dot_kernel<<<dim3(2048), dim3(256), 0, stream>>>(h, cls_w, tok_dot);
    select_kernel<<<dim3(B_), dim3(256), 0, stream>>>(tok_dot, ind, cls_b,
                                                      out_selected, out_logits, sel_ws);
    mask_kernel<<<dim3(B_ * S_ / 4), dim3(256), 0, stream>>>(h, ind, sel_ws, out_mask, out_masked);
}